// Round 1
// baseline (84.692 us; speedup 1.0000x reference)
//
#include <hip/hip_runtime.h>
#include <hip/hip_bf16.h>
#include <math.h>

#define BB 32
#define NN 102400
#define TT 64
#define SS 1600
#define K3N (3 * NN)          // 307200
#define KC 256                // K-chunk for GEMM1
#define G1 400                // blocks for GEMM1
#define NCHUNK (K3N / KC)     // 1200
#define PI_F 3.14159265358979323846f

// ---------------- K1: GEMM1 partials: h_part[blk][b*32+c] = sum_k x[b,k]*w1[k,c]
__global__ __launch_bounds__(256) void k1_gemm(const float* __restrict__ x,
                                               const float* __restrict__ w1,
                                               float* __restrict__ h_part) {
    __shared__ float xs[32 * 260];       // [b][k] padded (260) -> conflict-free
    __shared__ float ws1[KC * 32];       // [k][c] linear
    const int tid = threadIdx.x;
    const int b = tid >> 3, cq = tid & 7;
    float a0 = 0.f, a1 = 0.f, a2 = 0.f, a3 = 0.f;

    for (int chunk = blockIdx.x; chunk < NCHUNK; chunk += G1) {
        const int k0 = chunk * KC;
        // stage x: 32 rows x 64 float4
        for (int i = tid; i < 32 * 64; i += 256) {
            const int bb = i >> 6, k4 = i & 63;
            const float4 v = *(const float4*)(x + (size_t)bb * 6 * NN + k0 + k4 * 4);
            *(float4*)(xs + bb * 260 + k4 * 4) = v;
        }
        // stage w1: 2048 contiguous float4
        for (int i = tid; i < (KC * 32) / 4; i += 256) {
            *(float4*)(ws1 + i * 4) = *(const float4*)(w1 + (size_t)k0 * 32 + i * 4);
        }
        __syncthreads();
        const float* xrow = xs + b * 260;
        #pragma unroll 8
        for (int k4 = 0; k4 < 64; ++k4) {
            const float4 xv = *(const float4*)(xrow + k4 * 4);
            #pragma unroll
            for (int j = 0; j < 4; ++j) {
                const float xj = j == 0 ? xv.x : (j == 1 ? xv.y : (j == 2 ? xv.z : xv.w));
                const float4 wv = *(const float4*)(ws1 + (k4 * 4 + j) * 32 + cq * 4);
                a0 = fmaf(xj, wv.x, a0);
                a1 = fmaf(xj, wv.y, a1);
                a2 = fmaf(xj, wv.z, a2);
                a3 = fmaf(xj, wv.w, a3);
            }
        }
        __syncthreads();
    }
    float4 r; r.x = a0; r.y = a1; r.z = a2; r.w = a3;
    *(float4*)(h_part + (size_t)blockIdx.x * 1024 + tid * 4) = r;
}

// ---------------- K2a: reduce partials -> h = relu(. + b1)
__global__ void k2a_reduce(const float* __restrict__ h_part, const float* __restrict__ b1,
                           float* __restrict__ h) {
    const int i = blockIdx.x * blockDim.x + threadIdx.x; // 0..1023, i = b*32+c
    float s = 0.f;
    for (int j = 0; j < G1; ++j) s += h_part[(size_t)j * 1024 + i];
    s += b1[i & 31];
    h[i] = fmaxf(s, 0.f);
}

// ---------------- K2b: rigid transform params per (b,t): store M = R^T (3x3) and T (3)
__global__ void k2b_rigid(const float* __restrict__ h, const float* __restrict__ w2,
                          const float* __restrict__ b2, const float* __restrict__ sz,
                          float* __restrict__ RT) {
    const int g = blockIdx.x * blockDim.x + threadIdx.x;
    if (g >= BB * TT) return;
    const int b = g / TT, t = g % TT;
    const float* hb = h + b * 32;
    float z[3];
    #pragma unroll
    for (int j = 0; j < 3; ++j) {
        const int col = 6 * t + 3 + j;
        float s = b2[col];
        #pragma unroll 8
        for (int c = 0; c < 32; ++c) s = fmaf(hb[c], w2[c * 384 + col], s);
        z[j] = tanhf(s);
    }
    float c0, s0, c1, s1, c2, s2;
    sincosf(PI_F * z[0], &s0, &c0);
    sincosf(PI_F * z[1], &s1, &c1);
    sincosf(PI_F * z[2], &s2, &c2);
    // XYZ = Rz(a0) @ Ry(a1) @ Rx(a2)  (per reference stacking)
    const float R00 = c0 * c1;
    const float R01 = -s0 * c2 + c0 * s1 * s2;
    const float R02 = s0 * s2 + c0 * s1 * c2;
    const float R10 = s0 * c1;
    const float R11 = c0 * c2 + s0 * s1 * s2;
    const float R12 = -c0 * s2 + s0 * s1 * c2;
    const float R20 = -s1;
    const float R21 = c1 * s2;
    const float R22 = c1 * c2;
    const float szx = sz[0], szy = sz[1], szz = sz[2];
    const float cx = 0.5f * szx, cy = 0.5f * szy, cz = 0.5f * szz;
    const float T0 = z[0] * szx + cx - (cx * R00 + cy * R10 + cz * R20);
    const float T1 = z[1] * szy + cy - (cx * R01 + cy * R11 + cz * R21);
    const float T2 = z[2] * szz + cz - (cx * R02 + cy * R12 + cz * R22);
    float* o = RT + g * 12;
    // store M[j][k] = R[k][j] rows with T appended: y_j = M[j].x3 + T_j
    o[0] = R00; o[1] = R10; o[2] = R20; o[3]  = T0;
    o[4] = R01; o[5] = R11; o[6] = R21; o[7]  = T1;
    o[8] = R02; o[9] = R12; o[10] = R22; o[11] = T2;
}

// ---------------- K3: transform + scatter + hi-copy + pts2 accumulation
__global__ __launch_bounds__(256) void k3_transform(const float* __restrict__ x,
                                                    const int* __restrict__ tess,
                                                    const float* __restrict__ RT,
                                                    float* __restrict__ out,
                                                    float* __restrict__ pts2) {
    const int blk = blockIdx.x;
    const int b = blk / TT, t = blk % TT;
    const float* p = RT + blk * 12;
    const float M00 = p[0], M01 = p[1], M02 = p[2], T0 = p[3];
    const float M10 = p[4], M11 = p[5], M12 = p[6], T1 = p[7];
    const float M20 = p[8], M21 = p[9], M22 = p[10], T2 = p[11];
    const float* xb = x + (size_t)b * 6 * NN;
    float* ob = out + (size_t)b * 6 * NN;
    const int* tr = tess + t * SS;
    float s0 = 0.f, s1 = 0.f, s2 = 0.f;
    for (int s = threadIdx.x; s < SS; s += 256) {
        const int idx = tr[s];
        const float x0 = xb[idx], x1 = xb[NN + idx], x2 = xb[2 * NN + idx];
        const float y0 = fmaf(M00, x0, fmaf(M01, x1, fmaf(M02, x2, T0)));
        const float y1 = fmaf(M10, x0, fmaf(M11, x1, fmaf(M12, x2, T1)));
        const float y2 = fmaf(M20, x0, fmaf(M21, x1, fmaf(M22, x2, T2)));
        ob[idx] = y0; ob[NN + idx] = y1; ob[2 * NN + idx] = y2;
        s0 += y0; s1 += y1; s2 += y2;
        const int n = t * SS + s;
        ob[3 * NN + n] = xb[3 * NN + n];
        ob[4 * NN + n] = xb[4 * NN + n];
        ob[5 * NN + n] = xb[5 * NN + n];
    }
    // block reduce 3 sums
    #pragma unroll
    for (int o = 32; o > 0; o >>= 1) {
        s0 += __shfl_down(s0, o, 64);
        s1 += __shfl_down(s1, o, 64);
        s2 += __shfl_down(s2, o, 64);
    }
    __shared__ float red[4 * 3];
    const int lane = threadIdx.x & 63, wv = threadIdx.x >> 6;
    if (lane == 0) { red[wv * 3] = s0; red[wv * 3 + 1] = s1; red[wv * 3 + 2] = s2; }
    __syncthreads();
    if (threadIdx.x < 3) {
        const float s = red[threadIdx.x] + red[3 + threadIdx.x] + red[6 + threadIdx.x] + red[9 + threadIdx.x];
        pts2[blk * 3 + threadIdx.x] = s * (1.0f / SS);
    }
}

// ---------------- K4: pts1[t][j] = mean_s A[j][tess[t,s]]
__global__ __launch_bounds__(256) void k4_pts1(const float* __restrict__ A,
                                               const int* __restrict__ tess,
                                               float* __restrict__ pts1) {
    const int t = blockIdx.x;
    const int* tr = tess + t * SS;
    float s0 = 0.f, s1 = 0.f, s2 = 0.f;
    for (int s = threadIdx.x; s < SS; s += 256) {
        const int idx = tr[s];
        s0 += A[idx]; s1 += A[NN + idx]; s2 += A[2 * NN + idx];
    }
    #pragma unroll
    for (int o = 32; o > 0; o >>= 1) {
        s0 += __shfl_down(s0, o, 64);
        s1 += __shfl_down(s1, o, 64);
        s2 += __shfl_down(s2, o, 64);
    }
    __shared__ float red[4 * 3];
    const int lane = threadIdx.x & 63, wv = threadIdx.x >> 6;
    if (lane == 0) { red[wv * 3] = s0; red[wv * 3 + 1] = s1; red[wv * 3 + 2] = s2; }
    __syncthreads();
    if (threadIdx.x < 3) {
        const float s = red[threadIdx.x] + red[3 + threadIdx.x] + red[6 + threadIdx.x] + red[9 + threadIdx.x];
        pts1[t * 3 + threadIdx.x] = s * (1.0f / SS);
    }
}

// ---------------- K5: reg[b] = sum_{t,u} (mask[t,u]*(d1[t,u]-d2[b,t,u]))^2
__global__ __launch_bounds__(256) void k5_reg(const float* __restrict__ pts1,
                                              const float* __restrict__ pts2,
                                              const float* __restrict__ mask,
                                              float* __restrict__ out) {
    const int b = blockIdx.x;
    __shared__ float p1[TT * 3], p2[TT * 3];
    for (int i = threadIdx.x; i < TT * 3; i += 256) {
        p1[i] = pts1[i];
        p2[i] = pts2[b * TT * 3 + i];
    }
    __syncthreads();
    float acc = 0.f;
    for (int pr = threadIdx.x; pr < TT * TT; pr += 256) {
        const int t = pr >> 6, u = pr & 63;
        float dx = p1[t * 3] - p1[u * 3];
        float dy = p1[t * 3 + 1] - p1[u * 3 + 1];
        float dz = p1[t * 3 + 2] - p1[u * 3 + 2];
        const float d1 = sqrtf(dx * dx + dy * dy + dz * dz + 1e-12f);
        dx = p2[t * 3] - p2[u * 3];
        dy = p2[t * 3 + 1] - p2[u * 3 + 1];
        dz = p2[t * 3 + 2] - p2[u * 3 + 2];
        const float d2 = sqrtf(dx * dx + dy * dy + dz * dz + 1e-12f);
        const float d = mask[pr] * (d1 - d2);
        acc = fmaf(d, d, acc);
    }
    #pragma unroll
    for (int o = 32; o > 0; o >>= 1) acc += __shfl_down(acc, o, 64);
    __shared__ float red[4];
    const int lane = threadIdx.x & 63, wv = threadIdx.x >> 6;
    if (lane == 0) red[wv] = acc;
    __syncthreads();
    if (threadIdx.x == 0) {
        out[(size_t)BB * 6 * NN + b] = red[0] + red[1] + red[2] + red[3];
    }
}

extern "C" void kernel_launch(void* const* d_in, const int* in_sizes, int n_in,
                              void* d_out, int out_size, void* d_ws, size_t ws_size,
                              hipStream_t stream) {
    const float* x    = (const float*)d_in[0];
    const float* w1   = (const float*)d_in[1];
    const float* b1   = (const float*)d_in[2];
    const float* w2   = (const float*)d_in[3];
    const float* b2   = (const float*)d_in[4];
    const float* A    = (const float*)d_in[5];
    const float* mask = (const float*)d_in[6];
    const float* sz   = (const float*)d_in[7];
    const int*   tess = (const int*)d_in[8];
    float* out = (float*)d_out;
    float* ws  = (float*)d_ws;

    float* h_part = ws;                       // G1*1024
    float* h      = h_part + G1 * 1024;       // 1024
    float* RT     = h + 1024;                 // 2048*12
    float* pts2   = RT + BB * TT * 12;        // 2048*3
    float* pts1   = pts2 + BB * TT * 3;       // 64*3

    k1_gemm<<<G1, 256, 0, stream>>>(x, w1, h_part);
    k2a_reduce<<<4, 256, 0, stream>>>(h_part, b1, h);
    k2b_rigid<<<(BB * TT + 255) / 256, 256, 0, stream>>>(h, w2, b2, sz, RT);
    k3_transform<<<BB * TT, 256, 0, stream>>>(x, tess, RT, out, pts2);
    k4_pts1<<<TT, 256, 0, stream>>>(A, tess, pts1);
    k5_reg<<<BB, 256, 0, stream>>>(pts1, pts2, mask, out);
}